// Round 12
// baseline (4614.790 us; speedup 1.0000x reference)
//
#include <hip/hip_runtime.h>
#include <math.h>

#define NTOK 50257
#define NPC  225
#define NCLS 224
#define NH   1024
#define G4   4096
#define TSTEPS 128
#define BB   64
#define NN   8192
#define RBLK 128          // k_rec blocks; each owns 8 hidden cols

typedef __attribute__((ext_vector_type(8))) short bf16x8;
typedef __attribute__((ext_vector_type(4))) float f32x4;
typedef unsigned long long ull;

__device__ __forceinline__ float sigmf(float x){ return 1.0f/(1.0f+expf(-x)); }

__device__ __forceinline__ unsigned short f2bf(float f){
  unsigned u = __float_as_uint(f);
  unsigned r = u + 0x7fffu + ((u>>16)&1u);
  return (unsigned short)(r>>16);
}
__device__ __forceinline__ float bf2f(unsigned short s){
  return __uint_as_float(((unsigned)s)<<16);
}
__device__ __forceinline__ ull pack4(unsigned short a, unsigned short b,
                                     unsigned short c, unsigned short d){
  return (ull)a | ((ull)b<<16) | ((ull)c<<32) | ((ull)d<<48);
}

template<int AUX>
__device__ __forceinline__ void gl2lds16(const void* g, void* l){
  __builtin_amdgcn_global_load_lds(
      (const __attribute__((address_space(1))) unsigned int*)(g),
      (__attribute__((address_space(3))) unsigned int*)(l), 16, 0, AUX);
}

// flag-array grid barrier, fence-free (R9-proven); RBLK blocks co-resident.
__device__ __forceinline__ void gbar(unsigned* flags, unsigned ep){
  asm volatile("s_waitcnt vmcnt(0) lgkmcnt(0)" ::: "memory");
  __syncthreads();
  if (threadIdx.x==0)
    __hip_atomic_store(&flags[blockIdx.x], ep, __ATOMIC_RELAXED, __HIP_MEMORY_SCOPE_AGENT);
  if (threadIdx.x < RBLK)
    while (__hip_atomic_load(&flags[threadIdx.x], __ATOMIC_RELAXED, __HIP_MEMORY_SCOPE_AGENT) < ep)
      __builtin_amdgcn_s_sleep(2);
  __syncthreads();
}

// ---------------- embedding gather ----------------
__global__ void k_embed(const int* __restrict__ ids, const float* __restrict__ embW,
                        float* __restrict__ X){
  int n = blockIdx.x;
  int t = threadIdx.x;
  const float4* s = (const float4*)(embW + (size_t)ids[n]*NH);
  float4* d = (float4*)(X + (size_t)n*NH);
  d[t] = s[t];
}

// ---------------- fp32 -> bf16 hi/lo plane conversion ----------------
__global__ __launch_bounds__(256) void k_cvt(const float* __restrict__ src,
    unsigned short* __restrict__ dh, unsigned short* __restrict__ dl){
  int gid = blockIdx.x*256 + threadIdx.x;
  const float4* s = (const float4*)src + (size_t)gid*2;
  float4 a = s[0], b = s[1];
  unsigned short h0=f2bf(a.x),h1=f2bf(a.y),h2=f2bf(a.z),h3=f2bf(a.w);
  unsigned short h4=f2bf(b.x),h5=f2bf(b.y),h6=f2bf(b.z),h7=f2bf(b.w);
  ull* dh8 = (ull*)(dh + (size_t)gid*8);
  dh8[0] = pack4(h0,h1,h2,h3); dh8[1] = pack4(h4,h5,h6,h7);
  ull* dl8 = (ull*)(dl + (size_t)gid*8);
  dl8[0] = pack4(f2bf(a.x-bf2f(h0)), f2bf(a.y-bf2f(h1)), f2bf(a.z-bf2f(h2)), f2bf(a.w-bf2f(h3)));
  dl8[1] = pack4(f2bf(b.x-bf2f(h4)), f2bf(b.y-bf2f(h5)), f2bf(b.z-bf2f(h6)), f2bf(b.w-bf2f(h7)));
}

// ---------------- split-bf16 MFMA GEMM (R11, unchanged) ----------------
#define STAGE3(kt, bf) { \
  const unsigned short* Ap_ = ((kt)<32)? Ah : Al; \
  const unsigned short* Bp_ = (((kt)<16)||((kt)>=32))? Bh : Bl; \
  int ktp_ = (kt)&15; \
  _Pragma("unroll") \
  for (int i_=0;i_<4;i_++){ \
    int row_ = i_*32 + w*8 + (lane>>3); \
    int gs_ = (lane&7) ^ (row_&7); \
    gl2lds16<0>(Ap_ + (size_t)(m0+row_)*1024 + ktp_*64 + gs_*8, \
                (void*)&As[bf][(i_*256 + w*64)*8]); \
  } \
  _Pragma("unroll") \
  for (int i_=0;i_<4;i_++){ \
    int row_ = i_*32 + w*8 + (lane>>3); \
    int gs_ = (lane&7) ^ (row_&7); \
    gl2lds16<0>(Bp_ + (size_t)(n0+row_)*1024 + ktp_*64 + gs_*8, \
                (void*)&Bs[bf][(i_*256 + w*64)*8]); \
  } }

#define COMP3(bf) { \
  _Pragma("unroll") \
  for (int kh_=0;kh_<2;kh_++){ \
    bf16x8 af_[4], bfr_[4]; \
    _Pragma("unroll") \
    for (int f_=0; f_<4; f_++){ \
      int ar_ = wm + f_*16 + l15; \
      int ag_ = (kh_*4+kg) ^ (ar_&7); \
      af_[f_] = *(const bf16x8*)&As[bf][(ar_*8 + ag_)*8]; \
      int br_ = wn + f_*16 + l15; \
      int bg_ = (kh_*4+kg) ^ (br_&7); \
      bfr_[f_] = *(const bf16x8*)&Bs[bf][(br_*8 + bg_)*8]; \
    } \
    _Pragma("unroll") \
    for (int fa_=0; fa_<4; fa_++) \
      _Pragma("unroll") \
      for (int fb_=0; fb_<4; fb_++) \
        acc[fa_][fb_] = __builtin_amdgcn_mfma_f32_16x16x32_bf16(af_[fa_], bfr_[fb_], acc[fa_][fb_], 0,0,0); \
  } }

#define WAITVM(N) asm volatile("s_waitcnt vmcnt(" #N ")" ::: "memory")

__global__ __launch_bounds__(256,1) void k_gemm3(
    const unsigned short* __restrict__ Ah, const unsigned short* __restrict__ Al,
    const unsigned short* __restrict__ Bh, const unsigned short* __restrict__ Bl,
    const float* __restrict__ bi, const float* __restrict__ bh,
    float* __restrict__ C)
{
  __shared__ unsigned short As[2][128*64];
  __shared__ unsigned short Bs[2][128*64];
  int m0 = blockIdx.x*128, n0 = blockIdx.y*128;
  int t = threadIdx.x, lane = t&63, w = t>>6;
  int wm = (w>>1)*64, wn = (w&1)*64;
  int l15 = lane&15, kg = lane>>4;
  f32x4 acc[4][4];
  #pragma unroll
  for (int i=0;i<4;i++){
    #pragma unroll
    for (int j=0;j<4;j++) acc[i][j] = (f32x4){0.f,0.f,0.f,0.f};
  }

  STAGE3(0,0);
  for (int kt=0; kt<48; kt++){
    __syncthreads();
    if (kt<47){ STAGE3(kt+1, (kt+1)&1); WAITVM(8); }
    else      { WAITVM(0); }
    __syncthreads();
    COMP3(kt&1);
  }

  #pragma unroll
  for (int fa=0; fa<4; fa++){
    #pragma unroll
    for (int i=0;i<4;i++){
      int m = m0 + wm + fa*16 + kg*4 + i;
      float bias = bi[m] + bh[m];
      #pragma unroll
      for (int fb=0; fb<4; fb++){
        C[(size_t)m*NN + n0 + wn + fb*16 + l15] = acc[fa][fb][i] + bias;
      }
    }
  }
}

// ---------------- persistent LSTM recurrence: 128 blocks, reg-staged B ----------------
// Block jj owns cols jj*8..+7 (32 gate rows). W hi/lo in LDS (128 KB, ^row&7
// granule swizzle). h B-fragments loaded straight to VGPRs via sc0|sc1 16B loads
// (3-group pipeline, exact vmcnt ledger). Per wave: batches w*16..+15, 2 row-tiles,
// 3 split-bf16 passes. Halves the per-step IF$ broadcast vs 256 blocks.

#define ISSUE_G(AH, AL, SB) { \
  _Pragma("unroll") \
  for (int s_=0;s_<8;s_++){ \
    asm volatile("global_load_dwordx4 %0, %2, off offset:%c4 sc0 sc1\n\t" \
                 "global_load_dwordx4 %1, %3, off offset:%c4 sc0 sc1" \
      : "=&v"(AH[s_]), "=&v"(AL[s_]) \
      : "v"(baseH), "v"(baseL), "i"(((SB)+s_)*64) \
      : "memory"); \
  } }

#define COMP_G(AH, AL, SB) { \
  _Pragma("unroll") \
  for (int s_=0;s_<8;s_++){ \
    int gsw_ = ((((SB)+s_)*4 + kg) ^ swz)<<3; \
    bf16x8 a0H = *(const bf16x8*)&wldsH[l15*1024 + gsw_]; \
    bf16x8 a0L = *(const bf16x8*)&wldsL[l15*1024 + gsw_]; \
    bf16x8 a1H = *(const bf16x8*)&wldsH[(16+l15)*1024 + gsw_]; \
    bf16x8 a1L = *(const bf16x8*)&wldsL[(16+l15)*1024 + gsw_]; \
    accA0 = __builtin_amdgcn_mfma_f32_16x16x32_bf16(a0H, AH[s_], accA0, 0,0,0); \
    accB0 = __builtin_amdgcn_mfma_f32_16x16x32_bf16(a0H, AL[s_], accB0, 0,0,0); \
    accC0 = __builtin_amdgcn_mfma_f32_16x16x32_bf16(a0L, AH[s_], accC0, 0,0,0); \
    accA1 = __builtin_amdgcn_mfma_f32_16x16x32_bf16(a1H, AH[s_], accA1, 0,0,0); \
    accB1 = __builtin_amdgcn_mfma_f32_16x16x32_bf16(a1H, AL[s_], accB1, 0,0,0); \
    accC1 = __builtin_amdgcn_mfma_f32_16x16x32_bf16(a1L, AH[s_], accC1, 0,0,0); \
  } }

#define SBAR __builtin_amdgcn_sched_barrier(0)

__global__ __launch_bounds__(256,1) void k_rec(
    const float* __restrict__ GT, const float* __restrict__ Wh,
    const float* __restrict__ h0, const float* __restrict__ c0,
    unsigned short* __restrict__ hbH, unsigned short* __restrict__ hbL,
    float* __restrict__ Y,
    float* __restrict__ hN, float* __restrict__ cN,
    unsigned* flags)
{
  __shared__ unsigned short wldsH[32*1024];   // 64 KB
  __shared__ unsigned short wldsL[32*1024];   // 64 KB
  __shared__ float glds[64][33];              // 8448 B (conflict-free stride)
  __shared__ float hvals[64][8];              // 2048 B   => 141,568 B total

  int jj = blockIdx.x, t = threadIdx.x;
  int jj8 = jj*8;

  // ---- W (32 gate rows) -> bf16 hi/lo, granule swizzle ^(row&7) ----
  for (int rr=0; rr<32; rr++){
    int grow = (rr>>3)*NH + jj8 + (rr&7);
    float4 w4 = *(const float4*)(Wh + (size_t)grow*NH + t*4);
    unsigned short h0_=f2bf(w4.x), h1_=f2bf(w4.y), h2_=f2bf(w4.z), h3_=f2bf(w4.w);
    unsigned short l0_=f2bf(w4.x-bf2f(h0_)), l1_=f2bf(w4.y-bf2f(h1_));
    unsigned short l2_=f2bf(w4.z-bf2f(h2_)), l3_=f2bf(w4.w-bf2f(h3_));
    int us = rr*1024 + (((t>>1) ^ (rr&7))<<3) + ((t&1)<<2);
    *(ull*)&wldsH[us] = pack4(h0_,h1_,h2_,h3_);
    *(ull*)&wldsL[us] = pack4(l0_,l1_,l2_,l3_);
  }

  // pointwise items: item0 = (b0 = t&63, c0 = t>>6); item1 = (b0, c1 = 4+(t>>6))
  int b0 = t&63, c0i = t>>6, c1i = 4 + (t>>6);
  // MFMA mapping
  int lane = t&63, w = t>>6, w16 = w*16;
  int l15 = lane&15, kg = lane>>4, swz = lane&7 & 7;
  swz = l15 & 7;

  float creg0 = c0[b0*NH + jj8 + c0i];
  float creg1 = c0[b0*NH + jj8 + c1i];
  hvals[b0][c0i] = h0[b0*NH + jj8 + c0i];
  hvals[b0][c1i] = h0[b0*NH + jj8 + c1i];
  __syncthreads();
  { // h0 -> bf16 planes (buffer 0)
    int sb = (t&127)>>1, half = t&1;
    float v0=hvals[sb][half*4+0], v1=hvals[sb][half*4+1];
    float v2=hvals[sb][half*4+2], v3=hvals[sb][half*4+3];
    unsigned short u0=f2bf(v0),u1=f2bf(v1),u2=f2bf(v2),u3=f2bf(v3);
    if (t<128){
      __hip_atomic_store((ull*)&hbH[(size_t)sb*1024 + jj8 + half*4],
          pack4(u0,u1,u2,u3), __ATOMIC_RELAXED, __HIP_MEMORY_SCOPE_AGENT);
    } else {
      __hip_atomic_store((ull*)&hbL[(size_t)sb*1024 + jj8 + half*4],
          pack4(f2bf(v0-bf2f(u0)),f2bf(v1-bf2f(u1)),f2bf(v2-bf2f(u2)),f2bf(v3-bf2f(u3))),
          __ATOMIC_RELAXED, __HIP_MEMORY_SCOPE_AGENT);
    }
  }
  unsigned ep = 1;
  gbar(flags, ep); ep++;

  for (int st=0; st<TSTEPS; st++){
    const size_t hsrc = (size_t)(st&1)*65536;
    const size_t hdst = (size_t)((st+1)&1)*65536;

    // GT loads first (retire before first WAITVM threshold)
    float gtv[4][2];
    #pragma unroll
    for (int g=0; g<4; g++){
      gtv[g][0] = GT[((size_t)g*NH + jj8 + c0i)*NN + st*64 + b0];
      gtv[g][1] = GT[((size_t)g*NH + jj8 + c1i)*NN + st*64 + b0];
    }
    SBAR;

    const unsigned short* baseH = hbH + hsrc + (size_t)(w16+l15)*1024 + kg*8;
    const unsigned short* baseL = hbL + hsrc + (size_t)(w16+l15)*1024 + kg*8;

    f32x4 accA0={0,0,0,0}, accB0={0,0,0,0}, accC0={0,0,0,0};
    f32x4 accA1={0,0,0,0}, accB1={0,0,0,0}, accC1={0,0,0,0};
    bf16x8 bhA[8], blA[8], bhB[8], blB[8], bhC[8], blC[8];

    ISSUE_G(bhA, blA, 0);
    ISSUE_G(bhB, blB, 8);
    ISSUE_G(bhC, blC, 16);        // out = 8(GT)+48 = 56
    WAITVM(32); SBAR;             // GT + groupA retired
    COMP_G(bhA, blA, 0);
    ISSUE_G(bhA, blA, 24);        // out = 48
    WAITVM(32); SBAR;             // groupB retired
    COMP_G(bhB, blB, 8);
    WAITVM(16); SBAR;             // groupC retired
    COMP_G(bhC, blC, 16);
    WAITVM(0);  SBAR;             // groupA(2) retired
    COMP_G(bhA, blA, 24);

    // D exchange: lane = batch w16+l15; rows kg*4+i (tile0) / 16+kg*4+i (tile1)
    #pragma unroll
    for (int i=0;i<4;i++){
      glds[w16+l15][kg*4+i]    = accA0[i]+accB0[i]+accC0[i];
      glds[w16+l15][16+kg*4+i] = accA1[i]+accB1[i]+accC1[i];
    }
    __syncthreads();
    // pointwise: gate rows r = g*8 + c
    float gi0 = glds[b0][ 0+c0i] + gtv[0][0];
    float gf0 = glds[b0][ 8+c0i] + gtv[1][0];
    float gg0 = glds[b0][16+c0i] + gtv[2][0];
    float go0 = glds[b0][24+c0i] + gtv[3][0];
    float cn0 = sigmf(gf0)*creg0 + sigmf(gi0)*tanhf(gg0);
    creg0 = cn0;
    float hv0 = sigmf(go0)*tanhf(cn0);
    float gi1 = glds[b0][ 0+c1i] + gtv[0][1];
    float gf1 = glds[b0][ 8+c1i] + gtv[1][1];
    float gg1 = glds[b0][16+c1i] + gtv[2][1];
    float go1 = glds[b0][24+c1i] + gtv[3][1];
    float cn1 = sigmf(gf1)*creg1 + sigmf(gi1)*tanhf(gg1);
    creg1 = cn1;
    float hv1 = sigmf(go1)*tanhf(cn1);
    hvals[b0][c0i] = hv0;
    hvals[b0][c1i] = hv1;
    if (st == TSTEPS-1){
      hN[b0*NH + jj8 + c0i] = hv0; cN[b0*NH + jj8 + c0i] = creg0;
      hN[b0*NH + jj8 + c1i] = hv1; cN[b0*NH + jj8 + c1i] = creg1;
    }
    __syncthreads();
    { // h store (hi/lo planes) + Y
      int sb = (t&127)>>1, half = t&1;
      float v0=hvals[sb][half*4+0], v1=hvals[sb][half*4+1];
      float v2=hvals[sb][half*4+2], v3=hvals[sb][half*4+3];
      unsigned short u0=f2bf(v0),u1=f2bf(v1),u2=f2bf(v2),u3=f2bf(v3);
      if (t<128){
        __hip_atomic_store((ull*)&hbH[hdst + (size_t)sb*1024 + jj8 + half*4],
            pack4(u0,u1,u2,u3), __ATOMIC_RELAXED, __HIP_MEMORY_SCOPE_AGENT);
        *(float4*)(Y + (size_t)(st*BB+sb)*NH + jj8 + half*4) = make_float4(v0,v1,v2,v3);
      } else {
        __hip_atomic_store((ull*)&hbL[hdst + (size_t)sb*1024 + jj8 + half*4],
            pack4(f2bf(v0-bf2f(u0)),f2bf(v1-bf2f(u1)),f2bf(v2-bf2f(u2)),f2bf(v3-bf2f(u3))),
            __ATOMIC_RELAXED, __HIP_MEMORY_SCOPE_AGENT);
      }
    }
    gbar(flags, ep); ep++;
  }
}

// ---------------- top logits ----------------
__global__ __launch_bounds__(256) void k_gemm_top(
    const float* __restrict__ X, const float* __restrict__ W,
    const float* __restrict__ bias, float* __restrict__ C)
{
  __shared__ float Xs[32][68];
  __shared__ float Ws[32][36];
  int n0 = blockIdx.x*64, c0 = blockIdx.y*32;
  int t = threadIdx.x;
  int tm = (t&15)*4;
  int tn = (t>>4)*2;
  int lr = t>>3, lk = (t&7)*4;
  float acc[4][2] = {{0.f}};
  for (int k0=0;k0<NH;k0+=32){
    float4 x0 = *(const float4*)(X + (size_t)(n0+lr)*NH + k0+lk);
    float4 x1 = *(const float4*)(X + (size_t)(n0+lr+32)*NH + k0+lk);
    float4 wv = *(const float4*)(W + (size_t)(k0 + (t>>3))*NCLS + c0 + (t&7)*4);
    __syncthreads();
    Xs[lk+0][lr]=x0.x; Xs[lk+1][lr]=x0.y; Xs[lk+2][lr]=x0.z; Xs[lk+3][lr]=x0.w;
    Xs[lk+0][lr+32]=x1.x; Xs[lk+1][lr+32]=x1.y; Xs[lk+2][lr+32]=x1.z; Xs[lk+3][lr+32]=x1.w;
    *(float4*)&Ws[t>>3][(t&7)*4] = wv;
    __syncthreads();
    #pragma unroll 8
    for (int kk=0;kk<32;kk++){
      float4 av = *(const float4*)&Xs[kk][tm];
      float2 bv = *(const float2*)&Ws[kk][tn];
      acc[0][0] += av.x*bv.x; acc[0][1] += av.x*bv.y;
      acc[1][0] += av.y*bv.x; acc[1][1] += av.y*bv.y;
      acc[2][0] += av.z*bv.x; acc[2][1] += av.z*bv.y;
      acc[3][0] += av.w*bv.x; acc[3][1] += av.w*bv.y;
    }
  }
  float bz0 = bias[c0+tn], bz1 = bias[c0+tn+1];
  #pragma unroll
  for (int i=0;i<4;i++){
    float2 o = make_float2(acc[i][0]+bz0, acc[i][1]+bz1);
    *(float2*)(C + (size_t)(n0+tm+i)*NCLS + c0+tn) = o;
  }
}

// ---------------- per-row top softmax pick ----------------
__global__ void k_top_pick(const float* __restrict__ TL, const int* __restrict__ tg,
                           float* __restrict__ ptop){
  int n = blockIdx.x*4 + (threadIdx.x>>6);
  int lane = threadIdx.x&63;
  const float* row = TL + (size_t)n*NCLS;
  float v[4]; float m = -1e30f;
  #pragma unroll
  for (int q=0;q<4;q++){ int c = lane + q*64; v[q] = (c<NCLS)? row[c] : -1e30f; m = fmaxf(m, v[q]); }
  for (int o=32;o;o>>=1) m = fmaxf(m, __shfl_xor(m,o));
  float s = 0.f;
  #pragma unroll
  for (int q=0;q<4;q++){ int c = lane + q*64; if (c<NCLS) s += expf(v[q]-m); }
  for (int o=32;o;o>>=1) s += __shfl_xor(s,o);
  if (lane==0){ int pt = tg[n]/NPC; ptop[n] = expf(row[pt]-m)/s; }
}

// ---------------- class bucketing ----------------
__global__ void k_zero(int* cnt, int* cur){ int t=threadIdx.x; if(t<NCLS){cnt[t]=0; cur[t]=0;} }
__global__ void k_hist(const int* __restrict__ tg, int* cnt){
  int n = blockIdx.x*256+threadIdx.x;
  if (n<NN) atomicAdd(&cnt[tg[n]/NPC],1);
}
__global__ void k_scan(const int* __restrict__ cnt, int* __restrict__ off){
  if (threadIdx.x==0 && blockIdx.x==0){ int a=0; for(int c=0;c<NCLS;c++){ off[c]=a; a+=cnt[c]; } off[NCLS]=a; }
}
__global__ void k_scatter(const int* __restrict__ tg, const int* __restrict__ off,
                          int* cur, int* __restrict__ perm){
  int n = blockIdx.x*256+threadIdx.x;
  if (n<NN){ int c = tg[n]/NPC; int p = atomicAdd(&cur[c],1); perm[off[c]+p] = n; }
}

// ---------------- per-class bottom GEMM + softmax pick + final product ----------------
__global__ __launch_bounds__(256) void k_bot(
    const float* __restrict__ X, const float* __restrict__ botW, const float* __restrict__ botb,
    const int* __restrict__ tg, const int* __restrict__ off, const int* __restrict__ perm,
    const float* __restrict__ ptop, float* __restrict__ outP)
{
  int cls = blockIdx.x;
  int s = off[cls], e = off[cls+1];
  if (s>=e) return;
  __shared__ float xs[16][NH];
  __shared__ float lg[16][228];
  int t = threadIdx.x;
  const float* Wc = botW + (size_t)cls*NH*NPC;
  for (int base=s; base<e; base+=16){
    int nr = min(16, e-base);
    __syncthreads();
    for (int r=0;r<nr;r++){
      int n = perm[base+r];
      *(float4*)&xs[r][t*4] = *(const float4*)(X + (size_t)n*NH + t*4);
    }
    __syncthreads();
    if (t < NPC){
      float acc[16];
      #pragma unroll
      for (int r=0;r<16;r++) acc[r]=0.f;
      for (int k=0;k<NH;k+=2){
        float w0 = Wc[(size_t)k*NPC + t];
        float w1 = Wc[(size_t)(k+1)*NPC + t];
        #pragma unroll
        for (int r=0;r<16;r++){
          float2 x2 = *(const float2*)&xs[r][k];
          acc[r] += x2.x*w0 + x2.y*w1;
        }
      }
      float bb = botb[(size_t)cls*NPC + t];
      for (int r=0;r<nr;r++) lg[r][t] = acc[r] + bb;
    }
    __syncthreads();
    int wv = t>>6, lane = t&63;
    for (int r=wv; r<nr; r+=4){
      float v[4]; float m=-1e30f;
      #pragma unroll
      for (int q=0;q<4;q++){ int c = lane+q*64; v[q] = (c<NPC)? lg[r][c] : -1e30f; m=fmaxf(m,v[q]); }
      for (int o=32;o;o>>=1) m=fmaxf(m,__shfl_xor(m,o));
      float ss=0.f;
      #pragma unroll
      for (int q=0;q<4;q++){ int c = lane+q*64; if (c<NPC) ss += expf(v[q]-m); }
      for (int o=32;o;o>>=1) ss += __shfl_xor(ss,o);
      if (lane==0){
        int n = perm[base+r]; int pb = tg[n]%NPC;
        outP[n] = ptop[n]*expf(lg[r][pb]-m)/ss;
      }
    }
  }
}

extern "C" void kernel_launch(void* const* d_in, const int* in_sizes, int n_in,
                              void* d_out, int out_size, void* d_ws, size_t ws_size,
                              hipStream_t stream)
{
  const int*   ids  = (const int*)d_in[0];
  const int*   tg   = (const int*)d_in[1];
  const float* h0   = (const float*)d_in[2];
  const float* c0   = (const float*)d_in[3];
  const float* embW = (const float*)d_in[4];
  const float* Wih  = (const float*)d_in[5];
  const float* Whh  = (const float*)d_in[6];
  const float* bih  = (const float*)d_in[7];
  const float* bhh  = (const float*)d_in[8];
  const float* topW = (const float*)d_in[9];
  const float* topb = (const float*)d_in[10];
  const float* botW = (const float*)d_in[11];
  const float* botb = (const float*)d_in[12];
  float* out = (float*)d_out;

  float* X  = (float*)d_ws;
  float* Yb = X  + (size_t)NN*NH;
  float* GT = Yb + (size_t)NN*NH;
  unsigned short* BhP = (unsigned short*)(GT + (size_t)G4*NN);
  unsigned short* BlP = BhP + (size_t)NN*NH;
  unsigned short* WhP = BlP + (size_t)NN*NH;
  unsigned short* WlP = WhP + (size_t)G4*NH;
  unsigned short* hbH = WlP + (size_t)G4*NH;
  unsigned short* hbL = hbH + 2*BB*NH;
  float* TL = (float*)(hbL + 2*BB*NH);
  float* pt = TL + (size_t)NN*NCLS;
  int* cnt  = (int*)(pt + NN);
  int* off  = cnt + NCLS;
  int* cur  = off + NCLS + 1;
  int* perm = cur + NCLS;
  unsigned* flags = (unsigned*)(perm + NN);

  k_embed<<<NN,256,0,stream>>>(ids, embW, X);

  for (int l=0; l<2; l++){
    const float* A   = Wih + (size_t)l*G4*NH;
    const float* Wl  = Whh + (size_t)l*G4*NH;
    const float* bi  = bih + (size_t)l*G4;
    const float* bh  = bhh + (size_t)l*G4;
    const float* Bx  = (l==0)? X : Yb;
    float*       Yo  = (l==0)? Yb : X;
    k_cvt<<<(G4*NH/8)/256,256,0,stream>>>(A,  WhP, WlP);
    k_cvt<<<(NN*NH/8)/256,256,0,stream>>>(Bx, BhP, BlP);
    k_gemm3<<<dim3(G4/128, NN/128),256,0,stream>>>(WhP, WlP, BhP, BlP, bi, bh, GT);
    const float* h0l = h0 + (size_t)l*BB*NH;
    const float* c0l = c0 + (size_t)l*BB*NH;
    float* hNl = out + NN + (size_t)l*BB*NH;
    float* cNl = out + NN + 2*(size_t)BB*NH + (size_t)l*BB*NH;
    (void)hipMemsetAsync(flags, 0, 256*sizeof(unsigned), stream);
    k_rec<<<RBLK,256,0,stream>>>(GT, Wl, h0l, c0l, hbH, hbL, Yo, hNl, cNl, flags);
  }

  k_gemm_top<<<dim3(128,7),256,0,stream>>>(X, topW, topb, TL);
  k_top_pick<<<NN/4,256,0,stream>>>(TL, tg, pt);
  k_zero<<<1,256,0,stream>>>(cnt, cur);
  k_hist<<<NN/256,256,0,stream>>>(tg, cnt);
  k_scan<<<1,1,0,stream>>>(cnt, off);
  k_scatter<<<NN/256,256,0,stream>>>(tg, off, cur, perm);
  k_bot<<<NCLS,256,0,stream>>>(X, botW, botb, tg, off, perm, pt, out);
}

// Round 13
// 4185.732 us; speedup vs baseline: 1.1025x; 1.1025x over previous
//
#include <hip/hip_runtime.h>
#include <math.h>

#define NTOK 50257
#define NPC  225
#define NCLS 224
#define NH   1024
#define G4   4096
#define TSTEPS 128
#define BB   64
#define NN   8192
#define SLOT 65536        // ushorts per ring slot: [64][1024]

typedef __attribute__((ext_vector_type(8))) short bf16x8;
typedef __attribute__((ext_vector_type(4))) float f32x4;
typedef unsigned long long ull;

__device__ __forceinline__ float sigmf(float x){ return 1.0f/(1.0f+expf(-x)); }

__device__ __forceinline__ unsigned short f2bf(float f){
  unsigned u = __float_as_uint(f);
  unsigned r = u + 0x7fffu + ((u>>16)&1u);
  return (unsigned short)(r>>16);
}
__device__ __forceinline__ float bf2f(unsigned short s){
  return __uint_as_float(((unsigned)s)<<16);
}
__device__ __forceinline__ ull pack4(unsigned short a, unsigned short b,
                                     unsigned short c, unsigned short d){
  return (ull)a | ((ull)b<<16) | ((ull)c<<32) | ((ull)d<<48);
}

// global->LDS DMA; AUX literal: 0 = normal cached (L2 path), 17 = SC0|SC1 coherent
template<int AUX>
__device__ __forceinline__ void gl2lds16(const void* g, void* l){
  __builtin_amdgcn_global_load_lds(
      (const __attribute__((address_space(1))) unsigned int*)(g),
      (__attribute__((address_space(3))) unsigned int*)(l), 16, 0, AUX);
}

// flag-array grid barrier, fence-free (R9-proven). 256 blocks co-resident.
__device__ __forceinline__ void gbar(unsigned* flags, unsigned ep){
  asm volatile("s_waitcnt vmcnt(0) lgkmcnt(0)" ::: "memory");
  __syncthreads();
  if (threadIdx.x==0)
    __hip_atomic_store(&flags[blockIdx.x], ep, __ATOMIC_RELAXED, __HIP_MEMORY_SCOPE_AGENT);
  while (__hip_atomic_load(&flags[threadIdx.x], __ATOMIC_RELAXED, __HIP_MEMORY_SCOPE_AGENT) < ep)
    __builtin_amdgcn_s_sleep(2);
  __syncthreads();
}

// ---------------- embedding gather ----------------
__global__ void k_embed(const int* __restrict__ ids, const float* __restrict__ embW,
                        float* __restrict__ X){
  int n = blockIdx.x;
  int t = threadIdx.x;
  const float4* s = (const float4*)(embW + (size_t)ids[n]*NH);
  float4* d = (float4*)(X + (size_t)n*NH);
  d[t] = s[t];
}

// ---------------- fp32 -> bf16 hi/lo plane conversion ----------------
__global__ __launch_bounds__(256) void k_cvt(const float* __restrict__ src,
    unsigned short* __restrict__ dh, unsigned short* __restrict__ dl){
  int gid = blockIdx.x*256 + threadIdx.x;
  const float4* s = (const float4*)src + (size_t)gid*2;
  float4 a = s[0], b = s[1];
  unsigned short h0=f2bf(a.x),h1=f2bf(a.y),h2=f2bf(a.z),h3=f2bf(a.w);
  unsigned short h4=f2bf(b.x),h5=f2bf(b.y),h6=f2bf(b.z),h7=f2bf(b.w);
  ull* dh8 = (ull*)(dh + (size_t)gid*8);
  dh8[0] = pack4(h0,h1,h2,h3); dh8[1] = pack4(h4,h5,h6,h7);
  ull* dl8 = (ull*)(dl + (size_t)gid*8);
  dl8[0] = pack4(f2bf(a.x-bf2f(h0)), f2bf(a.y-bf2f(h1)), f2bf(a.z-bf2f(h2)), f2bf(a.w-bf2f(h3)));
  dl8[1] = pack4(f2bf(b.x-bf2f(h4)), f2bf(b.y-bf2f(h5)), f2bf(b.z-bf2f(h6)), f2bf(b.w-bf2f(h7)));
}

// ---------------- split-bf16 MFMA GEMM (R11, unchanged) ----------------
#define STAGE3(kt, bf) { \
  const unsigned short* Ap_ = ((kt)<32)? Ah : Al; \
  const unsigned short* Bp_ = (((kt)<16)||((kt)>=32))? Bh : Bl; \
  int ktp_ = (kt)&15; \
  _Pragma("unroll") \
  for (int i_=0;i_<4;i_++){ \
    int row_ = i_*32 + w*8 + (lane>>3); \
    int gs_ = (lane&7) ^ (row_&7); \
    gl2lds16<0>(Ap_ + (size_t)(m0+row_)*1024 + ktp_*64 + gs_*8, \
                (void*)&As[bf][(i_*256 + w*64)*8]); \
  } \
  _Pragma("unroll") \
  for (int i_=0;i_<4;i_++){ \
    int row_ = i_*32 + w*8 + (lane>>3); \
    int gs_ = (lane&7) ^ (row_&7); \
    gl2lds16<0>(Bp_ + (size_t)(n0+row_)*1024 + ktp_*64 + gs_*8, \
                (void*)&Bs[bf][(i_*256 + w*64)*8]); \
  } }

#define COMP3(bf) { \
  _Pragma("unroll") \
  for (int kh_=0;kh_<2;kh_++){ \
    bf16x8 af_[4], bfr_[4]; \
    _Pragma("unroll") \
    for (int f_=0; f_<4; f_++){ \
      int ar_ = wm + f_*16 + l15; \
      int ag_ = (kh_*4+kg) ^ (ar_&7); \
      af_[f_] = *(const bf16x8*)&As[bf][(ar_*8 + ag_)*8]; \
      int br_ = wn + f_*16 + l15; \
      int bg_ = (kh_*4+kg) ^ (br_&7); \
      bfr_[f_] = *(const bf16x8*)&Bs[bf][(br_*8 + bg_)*8]; \
    } \
    _Pragma("unroll") \
    for (int fa_=0; fa_<4; fa_++) \
      _Pragma("unroll") \
      for (int fb_=0; fb_<4; fb_++) \
        acc[fa_][fb_] = __builtin_amdgcn_mfma_f32_16x16x32_bf16(af_[fa_], bfr_[fb_], acc[fa_][fb_], 0,0,0); \
  } }

#define WAITVM(N) asm volatile("s_waitcnt vmcnt(" #N ")" ::: "memory")

__global__ __launch_bounds__(256,1) void k_gemm3(
    const unsigned short* __restrict__ Ah, const unsigned short* __restrict__ Al,
    const unsigned short* __restrict__ Bh, const unsigned short* __restrict__ Bl,
    const float* __restrict__ bi, const float* __restrict__ bh,
    float* __restrict__ C)
{
  __shared__ unsigned short As[2][128*64];
  __shared__ unsigned short Bs[2][128*64];
  int m0 = blockIdx.x*128, n0 = blockIdx.y*128;
  int t = threadIdx.x, lane = t&63, w = t>>6;
  int wm = (w>>1)*64, wn = (w&1)*64;
  int l15 = lane&15, kg = lane>>4;
  f32x4 acc[4][4];
  #pragma unroll
  for (int i=0;i<4;i++){
    #pragma unroll
    for (int j=0;j<4;j++) acc[i][j] = (f32x4){0.f,0.f,0.f,0.f};
  }

  STAGE3(0,0);
  for (int kt=0; kt<48; kt++){
    __syncthreads();
    if (kt<47){ STAGE3(kt+1, (kt+1)&1); WAITVM(8); }
    else      { WAITVM(0); }
    __syncthreads();
    COMP3(kt&1);
  }

  #pragma unroll
  for (int fa=0; fa<4; fa++){
    #pragma unroll
    for (int i=0;i<4;i++){
      int m = m0 + wm + fa*16 + kg*4 + i;
      float bias = bi[m] + bh[m];
      #pragma unroll
      for (int fb=0; fb<4; fb++){
        C[(size_t)m*NN + n0 + wn + fb*16 + l15] = acc[fa][fb][i] + bias;
      }
    }
  }
}

// ---------------- persistent LSTM recurrence: 256 blocks, h ring over L2 ----------------
// Block jj owns hidden cols jj*4..+3 (16 gate rows); W hi/lo in LDS (64 KB).
// h exchanged via a 129-slot write-once ring: writers store-through (sc0 sc1)
// to slot st+1; readers DMA slot st with NORMAL CACHED loads (aux=0) -> per-XCD
// L2 serves the broadcast (first CU misses to IF$, rest hit L2). No stale lines:
// each ring address is written exactly once, before any read (barrier-ordered).

#define ISSUE_CHUNK(c, d) { \
  asm volatile("s_waitcnt lgkmcnt(0)" ::: "memory"); \
  const int hb_ = hreg + (d)*1024; \
  _Pragma("unroll") \
  for (int i_=0;i_<2;i_++){ \
    int rl_ = i_*8 + (lane>>3); \
    int sg_ = (lane&7) ^ (rl_&7); \
    size_t so_ = hsrc + (size_t)(w16 + rl_)*1024 + (size_t)(c)*64 + sg_*8; \
    gl2lds16<0>(hbH + so_, (void*)&hcH[hb_ + i_*512]); \
    gl2lds16<0>(hbL + so_, (void*)&hcL[hb_ + i_*512]); \
  } }

#define COMPUTE_CHUNK(c, d) { \
  const int hb_ = hreg + (d)*1024; \
  _Pragma("unroll") \
  for (int k2_=0;k2_<2;k2_++){ \
    int kidx_ = (c)*2 + k2_; \
    int ap_ = (((kidx_*4 + kg) ^ l7)<<3); \
    bf16x8 aH_ = *(const bf16x8*)&wldsH[l15*1024 + ap_]; \
    bf16x8 aL_ = *(const bf16x8*)&wldsL[l15*1024 + ap_]; \
    int bp_ = (((k2_*4 + kg) ^ l7)<<3); \
    bf16x8 bH_ = *(const bf16x8*)&hcH[hb_ + l15*64 + bp_]; \
    bf16x8 bL_ = *(const bf16x8*)&hcL[hb_ + l15*64 + bp_]; \
    accA = __builtin_amdgcn_mfma_f32_16x16x32_bf16(aH_, bH_, accA, 0,0,0); \
    accB = __builtin_amdgcn_mfma_f32_16x16x32_bf16(aH_, bL_, accB, 0,0,0); \
    accC = __builtin_amdgcn_mfma_f32_16x16x32_bf16(aL_, bH_, accC, 0,0,0); \
  } }

__global__ __launch_bounds__(256,1) void k_rec(
    const float* __restrict__ GT, const float* __restrict__ Wh,
    const float* __restrict__ h0, const float* __restrict__ c0,
    unsigned short* __restrict__ hbH, unsigned short* __restrict__ hbL,
    float* __restrict__ Y,
    float* __restrict__ hN, float* __restrict__ cN,
    unsigned* flags)
{
  __shared__ unsigned short wldsH[16*1024];
  __shared__ unsigned short wldsL[16*1024];
  __shared__ unsigned short hcH[16*1024];
  __shared__ unsigned short hcL[16*1024];
  __shared__ float glds[64][20];
  __shared__ float hvals[64][5];

  int jj = blockIdx.x, t = threadIdx.x;
  int jj4 = jj*4;

  for (int rr=0; rr<16; rr++){
    int grow = (rr>>2)*NH + jj4 + (rr&3);
    float4 w4 = *(const float4*)(Wh + (size_t)grow*NH + t*4);
    unsigned short h0_=f2bf(w4.x), h1_=f2bf(w4.y), h2_=f2bf(w4.z), h3_=f2bf(w4.w);
    unsigned short l0_=f2bf(w4.x-bf2f(h0_)), l1_=f2bf(w4.y-bf2f(h1_));
    unsigned short l2_=f2bf(w4.z-bf2f(h2_)), l3_=f2bf(w4.w-bf2f(h3_));
    int us = rr*1024 + (((t>>1) ^ (rr&7))<<3) + ((t&1)<<2);
    *(ull*)&wldsH[us] = pack4(h0_,h1_,h2_,h3_);
    *(ull*)&wldsL[us] = pack4(l0_,l1_,l2_,l3_);
  }

  int b = t&63, cc = t>>6;
  int hc = jj4 + cc;
  int lane = t&63, w = t>>6, w16 = w*16;
  int l15 = lane&15, l7 = lane&7, kg = lane>>4;
  int hreg = w*4096;

  float creg = c0[b*NH + hc];
  hvals[b][cc] = h0[b*NH + hc];
  __syncthreads();
  { // h0 -> bf16 planes, ring slot 0
    int sb = t&63, which = t>>6;
    if (which<2){
      float v0=hvals[sb][0], v1=hvals[sb][1], v2=hvals[sb][2], v3=hvals[sb][3];
      unsigned short u0=f2bf(v0), u1=f2bf(v1), u2=f2bf(v2), u3=f2bf(v3);
      ull pv = (which==0) ? pack4(u0,u1,u2,u3)
             : pack4(f2bf(v0-bf2f(u0)), f2bf(v1-bf2f(u1)),
                     f2bf(v2-bf2f(u2)), f2bf(v3-bf2f(u3)));
      unsigned short* pl = (which==0) ? hbH : hbL;
      __hip_atomic_store((ull*)&pl[(size_t)sb*1024 + jj4], pv,
                         __ATOMIC_RELAXED, __HIP_MEMORY_SCOPE_AGENT);
    }
  }
  unsigned ep = 1;
  gbar(flags, ep); ep++;

  for (int st=0; st<TSTEPS; st++){
    const size_t hsrc = (size_t)st*SLOT;        // ring slot st (read, cached)
    const size_t hdst = (size_t)(st+1)*SLOT;    // ring slot st+1 (write-through)

    float gtv0 = GT[((size_t)0*NH + jj4 + cc)*NN + st*64 + b];
    float gtv1 = GT[((size_t)1*NH + jj4 + cc)*NN + st*64 + b];
    float gtv2 = GT[((size_t)2*NH + jj4 + cc)*NN + st*64 + b];
    float gtv3 = GT[((size_t)3*NH + jj4 + cc)*NN + st*64 + b];
    __builtin_amdgcn_sched_barrier(0);

    f32x4 accA = {0.f,0.f,0.f,0.f};
    f32x4 accB = {0.f,0.f,0.f,0.f};
    f32x4 accC = {0.f,0.f,0.f,0.f};

    ISSUE_CHUNK(0,0); ISSUE_CHUNK(1,1); ISSUE_CHUNK(2,2);
    for (int c=0;c<13;c++){
      ISSUE_CHUNK(c+3, (c+3)&3);
      WAITVM(12);
      COMPUTE_CHUNK(c, c&3);
    }
    WAITVM(8);  COMPUTE_CHUNK(13,1);
    WAITVM(4);  COMPUTE_CHUNK(14,2);
    WAITVM(0);  COMPUTE_CHUNK(15,3);

    glds[w16 + l15][kg*4+0] = accA[0]+accB[0]+accC[0];
    glds[w16 + l15][kg*4+1] = accA[1]+accB[1]+accC[1];
    glds[w16 + l15][kg*4+2] = accA[2]+accB[2]+accC[2];
    glds[w16 + l15][kg*4+3] = accA[3]+accB[3]+accC[3];
    __syncthreads();
    float gi = glds[b][0*4+cc] + gtv0;
    float gf = glds[b][1*4+cc] + gtv1;
    float gg = glds[b][2*4+cc] + gtv2;
    float go = glds[b][3*4+cc] + gtv3;
    float cnew = sigmf(gf)*creg + sigmf(gi)*tanhf(gg);
    creg = cnew;
    float hv = sigmf(go)*tanhf(cnew);
    hvals[b][cc] = hv;
    if (st == TSTEPS-1){ hN[b*NH+hc] = hv; cN[b*NH+hc] = creg; }
    __syncthreads();
    {
      int sb = t&63, which = t>>6;
      if (which<2){
        float v0=hvals[sb][0], v1=hvals[sb][1], v2=hvals[sb][2], v3=hvals[sb][3];
        unsigned short u0=f2bf(v0), u1=f2bf(v1), u2=f2bf(v2), u3=f2bf(v3);
        ull pv = (which==0) ? pack4(u0,u1,u2,u3)
               : pack4(f2bf(v0-bf2f(u0)), f2bf(v1-bf2f(u1)),
                       f2bf(v2-bf2f(u2)), f2bf(v3-bf2f(u3)));
        unsigned short* pl = (which==0) ? hbH : hbL;
        __hip_atomic_store((ull*)&pl[hdst + (size_t)sb*1024 + jj4], pv,
                           __ATOMIC_RELAXED, __HIP_MEMORY_SCOPE_AGENT);
      } else if (which==2){
        float4 yv = make_float4(hvals[sb][0],hvals[sb][1],hvals[sb][2],hvals[sb][3]);
        *(float4*)(Y + (size_t)(st*BB+sb)*NH + jj4) = yv;
      }
    }
    gbar(flags, ep); ep++;
  }
}

// ---------------- top logits ----------------
__global__ __launch_bounds__(256) void k_gemm_top(
    const float* __restrict__ X, const float* __restrict__ W,
    const float* __restrict__ bias, float* __restrict__ C)
{
  __shared__ float Xs[32][68];
  __shared__ float Ws[32][36];
  int n0 = blockIdx.x*64, c0 = blockIdx.y*32;
  int t = threadIdx.x;
  int tm = (t&15)*4;
  int tn = (t>>4)*2;
  int lr = t>>3, lk = (t&7)*4;
  float acc[4][2] = {{0.f}};
  for (int k0=0;k0<NH;k0+=32){
    float4 x0 = *(const float4*)(X + (size_t)(n0+lr)*NH + k0+lk);
    float4 x1 = *(const float4*)(X + (size_t)(n0+lr+32)*NH + k0+lk);
    float4 wv = *(const float4*)(W + (size_t)(k0 + (t>>3))*NCLS + c0 + (t&7)*4);
    __syncthreads();
    Xs[lk+0][lr]=x0.x; Xs[lk+1][lr]=x0.y; Xs[lk+2][lr]=x0.z; Xs[lk+3][lr]=x0.w;
    Xs[lk+0][lr+32]=x1.x; Xs[lk+1][lr+32]=x1.y; Xs[lk+2][lr+32]=x1.z; Xs[lk+3][lr+32]=x1.w;
    *(float4*)&Ws[t>>3][(t&7)*4] = wv;
    __syncthreads();
    #pragma unroll 8
    for (int kk=0;kk<32;kk++){
      float4 av = *(const float4*)&Xs[kk][tm];
      float2 bv = *(const float2*)&Ws[kk][tn];
      acc[0][0] += av.x*bv.x; acc[0][1] += av.x*bv.y;
      acc[1][0] += av.y*bv.x; acc[1][1] += av.y*bv.y;
      acc[2][0] += av.z*bv.x; acc[2][1] += av.z*bv.y;
      acc[3][0] += av.w*bv.x; acc[3][1] += av.w*bv.y;
    }
  }
  float bz0 = bias[c0+tn], bz1 = bias[c0+tn+1];
  #pragma unroll
  for (int i=0;i<4;i++){
    float2 o = make_float2(acc[i][0]+bz0, acc[i][1]+bz1);
    *(float2*)(C + (size_t)(n0+tm+i)*NCLS + c0+tn) = o;
  }
}

// ---------------- per-row top softmax pick ----------------
__global__ void k_top_pick(const float* __restrict__ TL, const int* __restrict__ tg,
                           float* __restrict__ ptop){
  int n = blockIdx.x*4 + (threadIdx.x>>6);
  int lane = threadIdx.x&63;
  const float* row = TL + (size_t)n*NCLS;
  float v[4]; float m = -1e30f;
  #pragma unroll
  for (int q=0;q<4;q++){ int c = lane + q*64; v[q] = (c<NCLS)? row[c] : -1e30f; m = fmaxf(m, v[q]); }
  for (int o=32;o;o>>=1) m = fmaxf(m, __shfl_xor(m,o));
  float s = 0.f;
  #pragma unroll
  for (int q=0;q<4;q++){ int c = lane + q*64; if (c<NCLS) s += expf(v[q]-m); }
  for (int o=32;o;o>>=1) s += __shfl_xor(s,o);
  if (lane==0){ int pt = tg[n]/NPC; ptop[n] = expf(row[pt]-m)/s; }
}

// ---------------- class bucketing ----------------
__global__ void k_zero(int* cnt, int* cur){ int t=threadIdx.x; if(t<NCLS){cnt[t]=0; cur[t]=0;} }
__global__ void k_hist(const int* __restrict__ tg, int* cnt){
  int n = blockIdx.x*256+threadIdx.x;
  if (n<NN) atomicAdd(&cnt[tg[n]/NPC],1);
}
__global__ void k_scan(const int* __restrict__ cnt, int* __restrict__ off){
  if (threadIdx.x==0 && blockIdx.x==0){ int a=0; for(int c=0;c<NCLS;c++){ off[c]=a; a+=cnt[c]; } off[NCLS]=a; }
}
__global__ void k_scatter(const int* __restrict__ tg, const int* __restrict__ off,
                          int* cur, int* __restrict__ perm){
  int n = blockIdx.x*256+threadIdx.x;
  if (n<NN){ int c = tg[n]/NPC; int p = atomicAdd(&cur[c],1); perm[off[c]+p] = n; }
}

// ---------------- per-class bottom GEMM + softmax pick + final product ----------------
__global__ __launch_bounds__(256) void k_bot(
    const float* __restrict__ X, const float* __restrict__ botW, const float* __restrict__ botb,
    const int* __restrict__ tg, const int* __restrict__ off, const int* __restrict__ perm,
    const float* __restrict__ ptop, float* __restrict__ outP)
{
  int cls = blockIdx.x;
  int s = off[cls], e = off[cls+1];
  if (s>=e) return;
  __shared__ float xs[16][NH];
  __shared__ float lg[16][228];
  int t = threadIdx.x;
  const float* Wc = botW + (size_t)cls*NH*NPC;
  for (int base=s; base<e; base+=16){
    int nr = min(16, e-base);
    __syncthreads();
    for (int r=0;r<nr;r++){
      int n = perm[base+r];
      *(float4*)&xs[r][t*4] = *(const float4*)(X + (size_t)n*NH + t*4);
    }
    __syncthreads();
    if (t < NPC){
      float acc[16];
      #pragma unroll
      for (int r=0;r<16;r++) acc[r]=0.f;
      for (int k=0;k<NH;k+=2){
        float w0 = Wc[(size_t)k*NPC + t];
        float w1 = Wc[(size_t)(k+1)*NPC + t];
        #pragma unroll
        for (int r=0;r<16;r++){
          float2 x2 = *(const float2*)&xs[r][k];
          acc[r] += x2.x*w0 + x2.y*w1;
        }
      }
      float bb = botb[(size_t)cls*NPC + t];
      for (int r=0;r<nr;r++) lg[r][t] = acc[r] + bb;
    }
    __syncthreads();
    int wv = t>>6, lane = t&63;
    for (int r=wv; r<nr; r+=4){
      float v[4]; float m=-1e30f;
      #pragma unroll
      for (int q=0;q<4;q++){ int c = lane+q*64; v[q] = (c<NPC)? lg[r][c] : -1e30f; m=fmaxf(m,v[q]); }
      for (int o=32;o;o>>=1) m=fmaxf(m,__shfl_xor(m,o));
      float ss=0.f;
      #pragma unroll
      for (int q=0;q<4;q++){ int c = lane+q*64; if (c<NPC) ss += expf(v[q]-m); }
      for (int o=32;o;o>>=1) ss += __shfl_xor(ss,o);
      if (lane==0){
        int n = perm[base+r]; int pb = tg[n]%NPC;
        outP[n] = ptop[n]*expf(lg[r][pb]-m)/ss;
      }
    }
  }
}

extern "C" void kernel_launch(void* const* d_in, const int* in_sizes, int n_in,
                              void* d_out, int out_size, void* d_ws, size_t ws_size,
                              hipStream_t stream)
{
  const int*   ids  = (const int*)d_in[0];
  const int*   tg   = (const int*)d_in[1];
  const float* h0   = (const float*)d_in[2];
  const float* c0   = (const float*)d_in[3];
  const float* embW = (const float*)d_in[4];
  const float* Wih  = (const float*)d_in[5];
  const float* Whh  = (const float*)d_in[6];
  const float* bih  = (const float*)d_in[7];
  const float* bhh  = (const float*)d_in[8];
  const float* topW = (const float*)d_in[9];
  const float* topb = (const float*)d_in[10];
  const float* botW = (const float*)d_in[11];
  const float* botb = (const float*)d_in[12];
  float* out = (float*)d_out;

  float* X  = (float*)d_ws;
  float* Yb = X  + (size_t)NN*NH;
  float* GT = Yb + (size_t)NN*NH;
  unsigned short* BhP = (unsigned short*)(GT + (size_t)G4*NN);
  unsigned short* BlP = BhP + (size_t)NN*NH;
  unsigned short* WhP = BlP + (size_t)NN*NH;
  unsigned short* WlP = WhP + (size_t)G4*NH;
  unsigned short* hbH = WlP + (size_t)G4*NH;        // ring: 129 slots x [64][1024]
  unsigned short* hbL = hbH + (size_t)(TSTEPS+1)*SLOT;
  float* TL = (float*)(hbL + (size_t)(TSTEPS+1)*SLOT);
  float* pt = TL + (size_t)NN*NCLS;
  int* cnt  = (int*)(pt + NN);
  int* off  = cnt + NCLS;
  int* cur  = off + NCLS + 1;
  int* perm = cur + NCLS;
  unsigned* flags = (unsigned*)(perm + NN);

  k_embed<<<NN,256,0,stream>>>(ids, embW, X);

  for (int l=0; l<2; l++){
    const float* A   = Wih + (size_t)l*G4*NH;
    const float* Wl  = Whh + (size_t)l*G4*NH;
    const float* bi  = bih + (size_t)l*G4;
    const float* bh  = bhh + (size_t)l*G4;
    const float* Bx  = (l==0)? X : Yb;
    float*       Yo  = (l==0)? Yb : X;
    k_cvt<<<(G4*NH/8)/256,256,0,stream>>>(A,  WhP, WlP);
    k_cvt<<<(NN*NH/8)/256,256,0,stream>>>(Bx, BhP, BlP);
    k_gemm3<<<dim3(G4/128, NN/128),256,0,stream>>>(WhP, WlP, BhP, BlP, bi, bh, GT);
    const float* h0l = h0 + (size_t)l*BB*NH;
    const float* c0l = c0 + (size_t)l*BB*NH;
    float* hNl = out + NN + (size_t)l*BB*NH;
    float* cNl = out + NN + 2*(size_t)BB*NH + (size_t)l*BB*NH;
    (void)hipMemsetAsync(flags, 0, 256*sizeof(unsigned), stream);
    k_rec<<<256,256,0,stream>>>(GT, Wl, h0l, c0l, hbH, hbL, Yo, hNl, cNl, flags);
  }

  k_gemm_top<<<dim3(128,7),256,0,stream>>>(X, topW, topb, TL);
  k_top_pick<<<NN/4,256,0,stream>>>(TL, tg, pt);
  k_zero<<<1,256,0,stream>>>(cnt, cur);
  k_hist<<<NN/256,256,0,stream>>>(tg, cnt);
  k_scan<<<1,1,0,stream>>>(cnt, off);
  k_scatter<<<NN/256,256,0,stream>>>(tg, off, cur, perm);
  k_bot<<<NCLS,256,0,stream>>>(X, botW, botb, tg, off, perm, pt, out);
}

// Round 14
// 3240.194 us; speedup vs baseline: 1.4242x; 1.2918x over previous
//
#include <hip/hip_runtime.h>
#include <math.h>

#define NTOK 50257
#define NPC  225
#define NCLS 224
#define NH   1024
#define G4   4096
#define TSTEPS 128
#define BB   64
#define NN   8192
#define SLOT 65536        // ushorts per ring slot: [64][1024]

typedef __attribute__((ext_vector_type(8))) short bf16x8;
typedef __attribute__((ext_vector_type(4))) float f32x4;
typedef unsigned long long ull;

__device__ __forceinline__ float sigmf(float x){ return 1.0f/(1.0f+expf(-x)); }

__device__ __forceinline__ unsigned short f2bf(float f){
  unsigned u = __float_as_uint(f);
  unsigned r = u + 0x7fffu + ((u>>16)&1u);
  return (unsigned short)(r>>16);
}
__device__ __forceinline__ float bf2f(unsigned short s){
  return __uint_as_float(((unsigned)s)<<16);
}
__device__ __forceinline__ ull pack4(unsigned short a, unsigned short b,
                                     unsigned short c, unsigned short d){
  return (ull)a | ((ull)b<<16) | ((ull)c<<32) | ((ull)d<<48);
}

// global->LDS DMA; AUX literal: 0 = normal cached, 17 = SC0|SC1 coherent
template<int AUX>
__device__ __forceinline__ void gl2lds16(const void* g, void* l){
  __builtin_amdgcn_global_load_lds(
      (const __attribute__((address_space(1))) unsigned int*)(g),
      (__attribute__((address_space(3))) unsigned int*)(l), 16, 0, AUX);
}

// flag-array grid barrier, fence-free (R9-proven). 256 blocks co-resident.
__device__ __forceinline__ void gbar(unsigned* flags, unsigned ep){
  asm volatile("s_waitcnt vmcnt(0) lgkmcnt(0)" ::: "memory");
  __syncthreads();
  if (threadIdx.x==0)
    __hip_atomic_store(&flags[blockIdx.x], ep, __ATOMIC_RELAXED, __HIP_MEMORY_SCOPE_AGENT);
  while (__hip_atomic_load(&flags[threadIdx.x], __ATOMIC_RELAXED, __HIP_MEMORY_SCOPE_AGENT) < ep)
    __builtin_amdgcn_s_sleep(2);
  __syncthreads();
}

// ---------------- embedding gather ----------------
__global__ void k_embed(const int* __restrict__ ids, const float* __restrict__ embW,
                        float* __restrict__ X){
  int n = blockIdx.x;
  int t = threadIdx.x;
  const float4* s = (const float4*)(embW + (size_t)ids[n]*NH);
  float4* d = (float4*)(X + (size_t)n*NH);
  d[t] = s[t];
}

// ---------------- fp32 -> bf16 hi/lo plane conversion ----------------
__global__ __launch_bounds__(256) void k_cvt(const float* __restrict__ src,
    unsigned short* __restrict__ dh, unsigned short* __restrict__ dl){
  int gid = blockIdx.x*256 + threadIdx.x;
  const float4* s = (const float4*)src + (size_t)gid*2;
  float4 a = s[0], b = s[1];
  unsigned short h0=f2bf(a.x),h1=f2bf(a.y),h2=f2bf(a.z),h3=f2bf(a.w);
  unsigned short h4=f2bf(b.x),h5=f2bf(b.y),h6=f2bf(b.z),h7=f2bf(b.w);
  ull* dh8 = (ull*)(dh + (size_t)gid*8);
  dh8[0] = pack4(h0,h1,h2,h3); dh8[1] = pack4(h4,h5,h6,h7);
  ull* dl8 = (ull*)(dl + (size_t)gid*8);
  dl8[0] = pack4(f2bf(a.x-bf2f(h0)), f2bf(a.y-bf2f(h1)), f2bf(a.z-bf2f(h2)), f2bf(a.w-bf2f(h3)));
  dl8[1] = pack4(f2bf(b.x-bf2f(h4)), f2bf(b.y-bf2f(h5)), f2bf(b.z-bf2f(h6)), f2bf(b.w-bf2f(h7)));
}

// ---------------- split-bf16 MFMA GEMM (R11, unchanged) ----------------
#define STAGE3(kt, bf) { \
  const unsigned short* Ap_ = ((kt)<32)? Ah : Al; \
  const unsigned short* Bp_ = (((kt)<16)||((kt)>=32))? Bh : Bl; \
  int ktp_ = (kt)&15; \
  _Pragma("unroll") \
  for (int i_=0;i_<4;i_++){ \
    int row_ = i_*32 + w*8 + (lane>>3); \
    int gs_ = (lane&7) ^ (row_&7); \
    gl2lds16<0>(Ap_ + (size_t)(m0+row_)*1024 + ktp_*64 + gs_*8, \
                (void*)&As[bf][(i_*256 + w*64)*8]); \
  } \
  _Pragma("unroll") \
  for (int i_=0;i_<4;i_++){ \
    int row_ = i_*32 + w*8 + (lane>>3); \
    int gs_ = (lane&7) ^ (row_&7); \
    gl2lds16<0>(Bp_ + (size_t)(n0+row_)*1024 + ktp_*64 + gs_*8, \
                (void*)&Bs[bf][(i_*256 + w*64)*8]); \
  } }

#define COMP3(bf) { \
  _Pragma("unroll") \
  for (int kh_=0;kh_<2;kh_++){ \
    bf16x8 af_[4], bfr_[4]; \
    _Pragma("unroll") \
    for (int f_=0; f_<4; f_++){ \
      int ar_ = wm + f_*16 + l15; \
      int ag_ = (kh_*4+kg) ^ (ar_&7); \
      af_[f_] = *(const bf16x8*)&As[bf][(ar_*8 + ag_)*8]; \
      int br_ = wn + f_*16 + l15; \
      int bg_ = (kh_*4+kg) ^ (br_&7); \
      bfr_[f_] = *(const bf16x8*)&Bs[bf][(br_*8 + bg_)*8]; \
    } \
    _Pragma("unroll") \
    for (int fa_=0; fa_<4; fa_++) \
      _Pragma("unroll") \
      for (int fb_=0; fb_<4; fb_++) \
        acc[fa_][fb_] = __builtin_amdgcn_mfma_f32_16x16x32_bf16(af_[fa_], bfr_[fb_], acc[fa_][fb_], 0,0,0); \
  } }

#define WAITVM(N) asm volatile("s_waitcnt vmcnt(" #N ")" ::: "memory")

__global__ __launch_bounds__(256,1) void k_gemm3(
    const unsigned short* __restrict__ Ah, const unsigned short* __restrict__ Al,
    const unsigned short* __restrict__ Bh, const unsigned short* __restrict__ Bl,
    const float* __restrict__ bi, const float* __restrict__ bh,
    float* __restrict__ C)
{
  __shared__ unsigned short As[2][128*64];
  __shared__ unsigned short Bs[2][128*64];
  int m0 = blockIdx.x*128, n0 = blockIdx.y*128;
  int t = threadIdx.x, lane = t&63, w = t>>6;
  int wm = (w>>1)*64, wn = (w&1)*64;
  int l15 = lane&15, kg = lane>>4;
  f32x4 acc[4][4];
  #pragma unroll
  for (int i=0;i<4;i++){
    #pragma unroll
    for (int j=0;j<4;j++) acc[i][j] = (f32x4){0.f,0.f,0.f,0.f};
  }

  STAGE3(0,0);
  for (int kt=0; kt<48; kt++){
    __syncthreads();
    if (kt<47){ STAGE3(kt+1, (kt+1)&1); WAITVM(8); }
    else      { WAITVM(0); }
    __syncthreads();
    COMP3(kt&1);
  }

  #pragma unroll
  for (int fa=0; fa<4; fa++){
    #pragma unroll
    for (int i=0;i<4;i++){
      int m = m0 + wm + fa*16 + kg*4 + i;
      float bias = bi[m] + bh[m];
      #pragma unroll
      for (int fb=0; fb<4; fb++){
        C[(size_t)m*NN + n0 + wn + fb*16 + l15] = acc[fa][fb][i] + bias;
      }
    }
  }
}

// ---------------- persistent LSTM recurrence: bf16-only h (half ingest) ----------------
// Block jj owns cols jj*4..+3 (16 gate rows); W hi/lo in LDS (64 KB).
// h stored once per step as SINGLE bf16 into a write-once ring slot; readers DMA
// with cached loads. Recurrent product = Wh*h + Wl*h (2 MFMA passes), fp32 acc.
// DMA: 2 bursts of 8 chunks (16 KB/wave in flight), one lgkm fence between.

#define ISSUE_CHUNK(c, d) { \
  const int hb_ = hreg + (d)*1024; \
  _Pragma("unroll") \
  for (int i_=0;i_<2;i_++){ \
    int rl_ = i_*8 + (lane>>3); \
    int sg_ = (lane&7) ^ (rl_&7); \
    size_t so_ = hsrc + (size_t)(w16 + rl_)*1024 + (size_t)(c)*64 + sg_*8; \
    gl2lds16<0>(hbH + so_, (void*)&hcH[hb_ + i_*512]); \
  } }

#define COMPUTE_CHUNK(c, d) { \
  const int hb_ = hreg + (d)*1024; \
  _Pragma("unroll") \
  for (int k2_=0;k2_<2;k2_++){ \
    int kidx_ = (c)*2 + k2_; \
    int ap_ = (((kidx_*4 + kg) ^ l7)<<3); \
    bf16x8 aH_ = *(const bf16x8*)&wldsH[l15*1024 + ap_]; \
    bf16x8 aL_ = *(const bf16x8*)&wldsL[l15*1024 + ap_]; \
    int bp_ = (((k2_*4 + kg) ^ l7)<<3); \
    bf16x8 bH_ = *(const bf16x8*)&hcH[hb_ + l15*64 + bp_]; \
    accA = __builtin_amdgcn_mfma_f32_16x16x32_bf16(aH_, bH_, accA, 0,0,0); \
    accC = __builtin_amdgcn_mfma_f32_16x16x32_bf16(aL_, bH_, accC, 0,0,0); \
  } }

__global__ __launch_bounds__(256,1) void k_rec(
    const float* __restrict__ GT, const float* __restrict__ Wh,
    const float* __restrict__ h0, const float* __restrict__ c0,
    unsigned short* __restrict__ hbH,
    float* __restrict__ Y,
    float* __restrict__ hN, float* __restrict__ cN,
    unsigned* flags)
{
  __shared__ unsigned short wldsH[16*1024];   // 32 KB
  __shared__ unsigned short wldsL[16*1024];   // 32 KB
  __shared__ unsigned short hcH[32*1024];     // 64 KB: 4 waves x 8 bufs x 1024
  __shared__ float glds[64][20];              // 5 KB
  __shared__ float hvals[64][5];              // 1.25 KB  => 134.4 KB total

  int jj = blockIdx.x, t = threadIdx.x;
  int jj4 = jj*4;

  for (int rr=0; rr<16; rr++){
    int grow = (rr>>2)*NH + jj4 + (rr&3);
    float4 w4 = *(const float4*)(Wh + (size_t)grow*NH + t*4);
    unsigned short h0_=f2bf(w4.x), h1_=f2bf(w4.y), h2_=f2bf(w4.z), h3_=f2bf(w4.w);
    unsigned short l0_=f2bf(w4.x-bf2f(h0_)), l1_=f2bf(w4.y-bf2f(h1_));
    unsigned short l2_=f2bf(w4.z-bf2f(h2_)), l3_=f2bf(w4.w-bf2f(h3_));
    int us = rr*1024 + (((t>>1) ^ (rr&7))<<3) + ((t&1)<<2);
    *(ull*)&wldsH[us] = pack4(h0_,h1_,h2_,h3_);
    *(ull*)&wldsL[us] = pack4(l0_,l1_,l2_,l3_);
  }

  int b = t&63, cc = t>>6;
  int hc = jj4 + cc;
  int lane = t&63, w = t>>6, w16 = w*16;
  int l15 = lane&15, l7 = lane&7, kg = lane>>4;
  int hreg = w*8192;    // per-wave region: 8 bufs x 1024 ushorts

  float creg = c0[b*NH + hc];
  hvals[b][cc] = h0[b*NH + hc];
  __syncthreads();
  { // h0 -> bf16, ring slot 0
    int sb = t&63, which = t>>6;
    if (which==0){
      float v0=hvals[sb][0], v1=hvals[sb][1], v2=hvals[sb][2], v3=hvals[sb][3];
      __hip_atomic_store((ull*)&hbH[(size_t)sb*1024 + jj4],
          pack4(f2bf(v0),f2bf(v1),f2bf(v2),f2bf(v3)),
          __ATOMIC_RELAXED, __HIP_MEMORY_SCOPE_AGENT);
    }
  }
  unsigned ep = 1;
  gbar(flags, ep); ep++;

  for (int st=0; st<TSTEPS; st++){
    const size_t hsrc = (size_t)st*SLOT;        // ring slot st (read, cached)
    const size_t hdst = (size_t)(st+1)*SLOT;    // ring slot st+1 (write-through)

    float gtv0 = GT[((size_t)0*NH + jj4 + cc)*NN + st*64 + b];
    float gtv1 = GT[((size_t)1*NH + jj4 + cc)*NN + st*64 + b];
    float gtv2 = GT[((size_t)2*NH + jj4 + cc)*NN + st*64 + b];
    float gtv3 = GT[((size_t)3*NH + jj4 + cc)*NN + st*64 + b];
    __builtin_amdgcn_sched_barrier(0);

    f32x4 accA = {0.f,0.f,0.f,0.f};
    f32x4 accC = {0.f,0.f,0.f,0.f};

    // burst 1: chunks 0..7 upfront (16 ops + 4 GT = 20 outstanding)
    ISSUE_CHUNK(0,0); ISSUE_CHUNK(1,1); ISSUE_CHUNK(2,2); ISSUE_CHUNK(3,3);
    ISSUE_CHUNK(4,4); ISSUE_CHUNK(5,5); ISSUE_CHUNK(6,6); ISSUE_CHUNK(7,7);
    WAITVM(16); __builtin_amdgcn_sched_barrier(0);   // GT retired
    WAITVM(14); COMPUTE_CHUNK(0,0);
    WAITVM(12); COMPUTE_CHUNK(1,1);
    WAITVM(10); COMPUTE_CHUNK(2,2);
    WAITVM(8);  COMPUTE_CHUNK(3,3);
    WAITVM(6);  COMPUTE_CHUNK(4,4);
    WAITVM(4);  COMPUTE_CHUNK(5,5);
    WAITVM(2);  COMPUTE_CHUNK(6,6);
    WAITVM(0);  COMPUTE_CHUNK(7,7);
    // all burst-1 reads consumed; fence LDS before buffer reuse
    asm volatile("s_waitcnt lgkmcnt(0)" ::: "memory");
    __builtin_amdgcn_sched_barrier(0);
    // burst 2: chunks 8..15 into bufs 0..7
    ISSUE_CHUNK(8,0); ISSUE_CHUNK(9,1); ISSUE_CHUNK(10,2); ISSUE_CHUNK(11,3);
    ISSUE_CHUNK(12,4); ISSUE_CHUNK(13,5); ISSUE_CHUNK(14,6); ISSUE_CHUNK(15,7);
    WAITVM(14); COMPUTE_CHUNK(8,0);
    WAITVM(12); COMPUTE_CHUNK(9,1);
    WAITVM(10); COMPUTE_CHUNK(10,2);
    WAITVM(8);  COMPUTE_CHUNK(11,3);
    WAITVM(6);  COMPUTE_CHUNK(12,4);
    WAITVM(4);  COMPUTE_CHUNK(13,5);
    WAITVM(2);  COMPUTE_CHUNK(14,6);
    WAITVM(0);  COMPUTE_CHUNK(15,7);

    glds[w16 + l15][kg*4+0] = accA[0]+accC[0];
    glds[w16 + l15][kg*4+1] = accA[1]+accC[1];
    glds[w16 + l15][kg*4+2] = accA[2]+accC[2];
    glds[w16 + l15][kg*4+3] = accA[3]+accC[3];
    __syncthreads();
    float gi = glds[b][0*4+cc] + gtv0;
    float gf = glds[b][1*4+cc] + gtv1;
    float gg = glds[b][2*4+cc] + gtv2;
    float go = glds[b][3*4+cc] + gtv3;
    float cnew = sigmf(gf)*creg + sigmf(gi)*tanhf(gg);
    creg = cnew;
    float hv = sigmf(go)*tanhf(cnew);
    hvals[b][cc] = hv;
    if (st == TSTEPS-1){ hN[b*NH+hc] = hv; cN[b*NH+hc] = creg; }
    __syncthreads();
    {
      int sb = t&63, which = t>>6;
      if (which==0){
        float v0=hvals[sb][0], v1=hvals[sb][1], v2=hvals[sb][2], v3=hvals[sb][3];
        __hip_atomic_store((ull*)&hbH[hdst + (size_t)sb*1024 + jj4],
            pack4(f2bf(v0),f2bf(v1),f2bf(v2),f2bf(v3)),
            __ATOMIC_RELAXED, __HIP_MEMORY_SCOPE_AGENT);
      } else if (which==2){
        float4 yv = make_float4(hvals[sb][0],hvals[sb][1],hvals[sb][2],hvals[sb][3]);
        *(float4*)(Y + (size_t)(st*BB+sb)*NH + jj4) = yv;
      }
    }
    gbar(flags, ep); ep++;
  }
}

// ---------------- top logits ----------------
__global__ __launch_bounds__(256) void k_gemm_top(
    const float* __restrict__ X, const float* __restrict__ W,
    const float* __restrict__ bias, float* __restrict__ C)
{
  __shared__ float Xs[32][68];
  __shared__ float Ws[32][36];
  int n0 = blockIdx.x*64, c0 = blockIdx.y*32;
  int t = threadIdx.x;
  int tm = (t&15)*4;
  int tn = (t>>4)*2;
  int lr = t>>3, lk = (t&7)*4;
  float acc[4][2] = {{0.f}};
  for (int k0=0;k0<NH;k0+=32){
    float4 x0 = *(const float4*)(X + (size_t)(n0+lr)*NH + k0+lk);
    float4 x1 = *(const float4*)(X + (size_t)(n0+lr+32)*NH + k0+lk);
    float4 wv = *(const float4*)(W + (size_t)(k0 + (t>>3))*NCLS + c0 + (t&7)*4);
    __syncthreads();
    Xs[lk+0][lr]=x0.x; Xs[lk+1][lr]=x0.y; Xs[lk+2][lr]=x0.z; Xs[lk+3][lr]=x0.w;
    Xs[lk+0][lr+32]=x1.x; Xs[lk+1][lr+32]=x1.y; Xs[lk+2][lr+32]=x1.z; Xs[lk+3][lr+32]=x1.w;
    *(float4*)&Ws[t>>3][(t&7)*4] = wv;
    __syncthreads();
    #pragma unroll 8
    for (int kk=0;kk<32;kk++){
      float4 av = *(const float4*)&Xs[kk][tm];
      float2 bv = *(const float2*)&Ws[kk][tn];
      acc[0][0] += av.x*bv.x; acc[0][1] += av.x*bv.y;
      acc[1][0] += av.y*bv.x; acc[1][1] += av.y*bv.y;
      acc[2][0] += av.z*bv.x; acc[2][1] += av.z*bv.y;
      acc[3][0] += av.w*bv.x; acc[3][1] += av.w*bv.y;
    }
  }
  float bz0 = bias[c0+tn], bz1 = bias[c0+tn+1];
  #pragma unroll
  for (int i=0;i<4;i++){
    float2 o = make_float2(acc[i][0]+bz0, acc[i][1]+bz1);
    *(float2*)(C + (size_t)(n0+tm+i)*NCLS + c0+tn) = o;
  }
}

// ---------------- per-row top softmax pick ----------------
__global__ void k_top_pick(const float* __restrict__ TL, const int* __restrict__ tg,
                           float* __restrict__ ptop){
  int n = blockIdx.x*4 + (threadIdx.x>>6);
  int lane = threadIdx.x&63;
  const float* row = TL + (size_t)n*NCLS;
  float v[4]; float m = -1e30f;
  #pragma unroll
  for (int q=0;q<4;q++){ int c = lane + q*64; v[q] = (c<NCLS)? row[c] : -1e30f; m = fmaxf(m, v[q]); }
  for (int o=32;o;o>>=1) m = fmaxf(m, __shfl_xor(m,o));
  float s = 0.f;
  #pragma unroll
  for (int q=0;q<4;q++){ int c = lane + q*64; if (c<NCLS) s += expf(v[q]-m); }
  for (int o=32;o;o>>=1) s += __shfl_xor(s,o);
  if (lane==0){ int pt = tg[n]/NPC; ptop[n] = expf(row[pt]-m)/s; }
}

// ---------------- class bucketing ----------------
__global__ void k_zero(int* cnt, int* cur){ int t=threadIdx.x; if(t<NCLS){cnt[t]=0; cur[t]=0;} }
__global__ void k_hist(const int* __restrict__ tg, int* cnt){
  int n = blockIdx.x*256+threadIdx.x;
  if (n<NN) atomicAdd(&cnt[tg[n]/NPC],1);
}
__global__ void k_scan(const int* __restrict__ cnt, int* __restrict__ off){
  if (threadIdx.x==0 && blockIdx.x==0){ int a=0; for(int c=0;c<NCLS;c++){ off[c]=a; a+=cnt[c]; } off[NCLS]=a; }
}
__global__ void k_scatter(const int* __restrict__ tg, const int* __restrict__ off,
                          int* cur, int* __restrict__ perm){
  int n = blockIdx.x*256+threadIdx.x;
  if (n<NN){ int c = tg[n]/NPC; int p = atomicAdd(&cur[c],1); perm[off[c]+p] = n; }
}

// ---------------- per-class bottom GEMM + softmax pick + final product ----------------
__global__ __launch_bounds__(256) void k_bot(
    const float* __restrict__ X, const float* __restrict__ botW, const float* __restrict__ botb,
    const int* __restrict__ tg, const int* __restrict__ off, const int* __restrict__ perm,
    const float* __restrict__ ptop, float* __restrict__ outP)
{
  int cls = blockIdx.x;
  int s = off[cls], e = off[cls+1];
  if (s>=e) return;
  __shared__ float xs[16][NH];
  __shared__ float lg[16][228];
  int t = threadIdx.x;
  const float* Wc = botW + (size_t)cls*NH*NPC;
  for (int base=s; base<e; base+=16){
    int nr = min(16, e-base);
    __syncthreads();
    for (int r=0;r<nr;r++){
      int n = perm[base+r];
      *(float4*)&xs[r][t*4] = *(const float4*)(X + (size_t)n*NH + t*4);
    }
    __syncthreads();
    if (t < NPC){
      float acc[16];
      #pragma unroll
      for (int r=0;r<16;r++) acc[r]=0.f;
      for (int k=0;k<NH;k+=2){
        float w0 = Wc[(size_t)k*NPC + t];
        float w1 = Wc[(size_t)(k+1)*NPC + t];
        #pragma unroll
        for (int r=0;r<16;r++){
          float2 x2 = *(const float2*)&xs[r][k];
          acc[r] += x2.x*w0 + x2.y*w1;
        }
      }
      float bb = botb[(size_t)cls*NPC + t];
      for (int r=0;r<nr;r++) lg[r][t] = acc[r] + bb;
    }
    __syncthreads();
    int wv = t>>6, lane = t&63;
    for (int r=wv; r<nr; r+=4){
      float v[4]; float m=-1e30f;
      #pragma unroll
      for (int q=0;q<4;q++){ int c = lane+q*64; v[q] = (c<NPC)? lg[r][c] : -1e30f; m=fmaxf(m,v[q]); }
      for (int o=32;o;o>>=1) m=fmaxf(m,__shfl_xor(m,o));
      float ss=0.f;
      #pragma unroll
      for (int q=0;q<4;q++){ int c = lane+q*64; if (c<NPC) ss += expf(v[q]-m); }
      for (int o=32;o;o>>=1) ss += __shfl_xor(ss,o);
      if (lane==0){
        int n = perm[base+r]; int pb = tg[n]%NPC;
        outP[n] = ptop[n]*expf(lg[r][pb]-m)/ss;
      }
    }
  }
}

extern "C" void kernel_launch(void* const* d_in, const int* in_sizes, int n_in,
                              void* d_out, int out_size, void* d_ws, size_t ws_size,
                              hipStream_t stream)
{
  const int*   ids  = (const int*)d_in[0];
  const int*   tg   = (const int*)d_in[1];
  const float* h0   = (const float*)d_in[2];
  const float* c0   = (const float*)d_in[3];
  const float* embW = (const float*)d_in[4];
  const float* Wih  = (const float*)d_in[5];
  const float* Whh  = (const float*)d_in[6];
  const float* bih  = (const float*)d_in[7];
  const float* bhh  = (const float*)d_in[8];
  const float* topW = (const float*)d_in[9];
  const float* topb = (const float*)d_in[10];
  const float* botW = (const float*)d_in[11];
  const float* botb = (const float*)d_in[12];
  float* out = (float*)d_out;

  float* X  = (float*)d_ws;
  float* Yb = X  + (size_t)NN*NH;
  float* GT = Yb + (size_t)NN*NH;
  unsigned short* BhP = (unsigned short*)(GT + (size_t)G4*NN);
  unsigned short* BlP = BhP + (size_t)NN*NH;
  unsigned short* WhP = BlP + (size_t)NN*NH;
  unsigned short* WlP = WhP + (size_t)G4*NH;
  unsigned short* hbH = WlP + (size_t)G4*NH;        // ring: 129 slots x [64][1024]
  float* TL = (float*)(hbH + (size_t)(TSTEPS+1)*SLOT);
  float* pt = TL + (size_t)NN*NCLS;
  int* cnt  = (int*)(pt + NN);
  int* off  = cnt + NCLS;
  int* cur  = off + NCLS + 1;
  int* perm = cur + NCLS;
  unsigned* flags = (unsigned*)(perm + NN);

  k_embed<<<NN,256,0,stream>>>(ids, embW, X);

  for (int l=0; l<2; l++){
    const float* A   = Wih + (size_t)l*G4*NH;
    const float* Wl  = Whh + (size_t)l*G4*NH;
    const float* bi  = bih + (size_t)l*G4;
    const float* bh  = bhh + (size_t)l*G4;
    const float* Bx  = (l==0)? X : Yb;
    float*       Yo  = (l==0)? Yb : X;
    k_cvt<<<(G4*NH/8)/256,256,0,stream>>>(A,  WhP, WlP);
    k_cvt<<<(NN*NH/8)/256,256,0,stream>>>(Bx, BhP, BlP);
    k_gemm3<<<dim3(G4/128, NN/128),256,0,stream>>>(WhP, WlP, BhP, BlP, bi, bh, GT);
    const float* h0l = h0 + (size_t)l*BB*NH;
    const float* c0l = c0 + (size_t)l*BB*NH;
    float* hNl = out + NN + (size_t)l*BB*NH;
    float* cNl = out + NN + 2*(size_t)BB*NH + (size_t)l*BB*NH;
    (void)hipMemsetAsync(flags, 0, 256*sizeof(unsigned), stream);
    k_rec<<<256,256,0,stream>>>(GT, Wl, h0l, c0l, hbH, Yo, hNl, cNl, flags);
  }

  k_gemm_top<<<dim3(128,7),256,0,stream>>>(X, topW, topb, TL);
  k_top_pick<<<NN/4,256,0,stream>>>(TL, tg, pt);
  k_zero<<<1,256,0,stream>>>(cnt, cur);
  k_hist<<<NN/256,256,0,stream>>>(tg, cnt);
  k_scan<<<1,1,0,stream>>>(cnt, off);
  k_scatter<<<NN/256,256,0,stream>>>(tg, off, cur, perm);
  k_bot<<<NCLS,256,0,stream>>>(X, botW, botb, tg, off, perm, pt, out);
}